// Round 6
// baseline (485.490 us; speedup 1.0000x reference)
//
#include <hip/hip_runtime.h>

#define BOX 71
#define NF 32
#define MAX_DIST_F 35.0f
#define NCELLS (BOX * BOX * BOX)                   // 357,911
#define SLICE_FLOATS (NCELLS * NF)                 // 11,453,152 floats (45.8 MB)
#define SLICE_BYTES  ((size_t)SLICE_FLOATS * 4)

// ===========================================================================
// Session model (R0-R5):
//  - Harness poisons the 4x-overallocated output (1.466 GB fill, ~239 us)
//    inside the timed window every iteration. Untouchable floor.
//  - Compulsory: write 366 MB of zeros/results. R1/R5 wrote slice 0 twice
//    (memset + atomic RMW): 239 + 58 + 31 = 328 us.
//  - This version: memset slices 1..7 only; CSR-bin the points (ws); gather
//    kernel writes slice 0 exactly once with plain coalesced stores.
//    No fp atomics -> immune to the R3/R4 dirty-L2/coherence regression.
//  - Gather accumulates each cell in ascending point order (= reference's
//    sequential order) to preserve bit-exactness (absmax 0.0).
// ===========================================================================

__device__ __forceinline__ bool point_cell(const float* __restrict__ coords,
                                           int p, int& cell) {
    float cx = coords[p * 3 + 0];
    float cy = coords[p * 3 + 1];
    float cz = coords[p * 3 + 2];
    // jnp.round = RNE; rintf matches. GRID_RES=1 so (c+35)/1 == c+35 exactly.
    int gx = (int)rintf(cx + MAX_DIST_F);
    int gy = (int)rintf(cy + MAX_DIST_F);
    int gz = (int)rintf(cz + MAX_DIST_F);
    bool in_box = (gx >= 0) & (gx < BOX) &
                  (gy >= 0) & (gy < BOX) &
                  (gz >= 0) & (gz < BOX);
    cell = (gx * BOX + gy) * BOX + gz;
    return in_box;
}

__global__ __launch_bounds__(256) void count_kernel(
    const float* __restrict__ coords, unsigned* __restrict__ cnt, int total_points)
{
    int p = blockIdx.x * 256 + threadIdx.x;
    if (p >= total_points) return;
    int c; if (!point_cell(coords, p, c)) return;
    atomicAdd(&cnt[c], 1u);
}

// Disjoint contiguous ranges via a global cursor; range order is irrelevant.
__global__ __launch_bounds__(256) void offsets_kernel(
    const unsigned* __restrict__ cnt, unsigned* __restrict__ offs,
    unsigned* __restrict__ cursor)
{
    int c = blockIdx.x * 256 + threadIdx.x;
    if (c >= NCELLS) return;
    unsigned n = cnt[c];
    if (n) offs[c] = atomicAdd(cursor, n);
}

__global__ __launch_bounds__(256) void fill_kernel(
    const float* __restrict__ coords, unsigned* __restrict__ fillc,
    const unsigned* __restrict__ offs, unsigned* __restrict__ bins,
    int total_points)
{
    int p = blockIdx.x * 256 + threadIdx.x;
    if (p >= total_points) return;
    int c; if (!point_cell(coords, p, c)) return;
    unsigned slot = atomicAdd(&fillc[c], 1u);
    bins[offs[c] + slot] = (unsigned)p;
}

// One 32-lane group per cell: lane f accumulates feature f over the cell's
// bin in ASCENDING point order (selection scan over the tiny bin; bins/count
// reads are lane-uniform -> broadcast; features reads are 128B coalesced).
// Single coalesced 128B store per cell -> slice 0 written exactly once.
__global__ __launch_bounds__(256) void gather_kernel(
    const float* __restrict__ features, const unsigned* __restrict__ cnt,
    const unsigned* __restrict__ offs, const unsigned* __restrict__ bins,
    float* __restrict__ grid)
{
    int t = blockIdx.x * 256 + threadIdx.x;
    int c = t >> 5;          // cell
    int f = t & 31;          // feature
    if (c >= NCELLS) return;

    int n = (int)cnt[c];
    float acc = 0.f;
    if (n) {
        unsigned off = offs[c];
        int prev = -1;
        for (int j = 0; j < n; ++j) {           // j-th smallest point index
            int m = 0x7fffffff;
            for (int i = 0; i < n; ++i) {
                int q = (int)bins[off + i];
                if (q > prev && q < m) m = q;
            }
            acc += features[(size_t)m * NF + f];
            prev = m;
        }
    }
    grid[(size_t)c * NF + f] = acc;
}

// ---- proven R5 fallback (used only if ws_size is insufficient) ----
__global__ __launch_bounds__(256) void MakeGrid_scatter_kernel(
    const float* __restrict__ coords, const float* __restrict__ features,
    float* __restrict__ grid, int total_points)
{
    int t = blockIdx.x * blockDim.x + threadIdx.x;
    int p = t >> 5, f = t & 31;
    if (p >= total_points) return;
    int c; if (!point_cell(coords, p, c)) return;
    float v = features[(size_t)p * NF + f];
#if defined(__AMDGCN__)
    unsafeAtomicAdd(grid + (size_t)c * NF + f, v);
#else
    atomicAdd(grid + (size_t)c * NF + f, v);
#endif
}

extern "C" void kernel_launch(void* const* d_in, const int* in_sizes, int n_in,
                              void* d_out, int out_size, void* d_ws, size_t ws_size,
                              hipStream_t stream) {
    const float* coords   = (const float*)d_in[0];  // [B,N,3] fp32
    const float* features = (const float*)d_in[1];  // [B,N,F] fp32
    float* out = (float*)d_out;                     // [B,71,71,71,F] fp32

    int total_points = in_sizes[0] / 3;             // B*N = 131072

    // ws layout (u32): cnt[NCELLS] | fillc[NCELLS] | cursor[1] | offs[NCELLS] | bins[total_points]
    size_t ws_need = ((size_t)3 * NCELLS + 1 + (size_t)total_points) * 4;
    if (ws_size < ws_need) {
        // Fallback: R5 path (328 us): full memset + atomic scatter.
        hipMemsetAsync(out, 0, (size_t)out_size, stream);
        int blocks = (total_points * NF + 255) / 256;
        MakeGrid_scatter_kernel<<<blocks, 256, 0, stream>>>(coords, features, out, total_points);
        return;
    }

    unsigned* wsb    = (unsigned*)d_ws;
    unsigned* cnt    = wsb;
    unsigned* fillc  = wsb + NCELLS;
    unsigned* cursor = wsb + 2 * (size_t)NCELLS;
    unsigned* offs   = wsb + 2 * (size_t)NCELLS + 1;
    unsigned* bins   = wsb + 3 * (size_t)NCELLS + 1;

    // 1) zero slices 1..7 (320.7 MB, compulsory; slice 0 is written by gather)
    hipMemsetAsync(out + SLICE_FLOATS, 0, 7 * SLICE_BYTES, stream);
    // 2) zero cnt+fillc+cursor (2.86 MB)
    hipMemsetAsync(wsb, 0, (2 * (size_t)NCELLS + 1) * 4, stream);

    int pblocks = (total_points + 255) / 256;       // 512
    int cblocks = (NCELLS + 255) / 256;             // 1399
    int gblocks = (NCELLS * NF + 255) / 256;        // 44,739

    count_kernel  <<<pblocks, 256, 0, stream>>>(coords, cnt, total_points);
    offsets_kernel<<<cblocks, 256, 0, stream>>>(cnt, offs, cursor);
    fill_kernel   <<<pblocks, 256, 0, stream>>>(coords, fillc, offs, bins, total_points);
    gather_kernel <<<gblocks, 256, 0, stream>>>(features, cnt, offs, bins, out);
}

// Round 7
// 333.803 us; speedup vs baseline: 1.4544x; 1.4544x over previous
//
#include <hip/hip_runtime.h>

#define BOX 71
#define NF 32
#define MAX_DIST_F 35.0f

// ===========================================================================
// Session model (R0-R6, six differentials):
//  - Harness poisons the 4x-overallocated output (1.466 GB fill, ~239 us)
//    INSIDE the timed window, same stream, every iteration. Untouchable:
//    overlapping it would race our zeroing of the same buffer.
//  - Compulsory: 366 MB of zero/result writes. Single rocclr fill ~58 us.
//  - Scatter ~31 us: ~3 us HBM (feature reads; atomic RMW lines are
//    fill-warm in the memory-side cache), rest is ATOMIC-OP THROUGHPUT.
//  - Restructures all regressed: R3 NT-zero 395, R4 fused zero+scatter 383,
//    R6 CSR gather 485. Cached stores over 100s of MB run ~2.4 TB/s vs the
//    fill's 6.3; extra dependent dispatches add latency. Keep the simple
//    structure: one fill + one scatter.
//  - This round: halve atomic count via packed global_atomic_pk_add_f32
//    (16 lanes/point, float2 per lane). Fallback = exact R5 (328.3 us).
// ===========================================================================

typedef float v2f __attribute__((ext_vector_type(2)));
#if defined(__has_builtin)
#if __has_builtin(__builtin_amdgcn_global_atomic_fadd_v2f32)
#define HAVE_PK_FADD 1
#endif
#endif

// One 16-lane group per point: lane k handles features {2k, 2k+1} as float2.
// features: 16 lanes x 8B = 128B coalesced per point.
// atomic target: 32 consecutive floats per point (coalesced burst), packed
// 2xf32 atomics halve op count vs scalar.
__global__ __launch_bounds__(256) void MakeGrid_scatter_kernel(
    const float* __restrict__ coords,
    const float* __restrict__ features,
    float* __restrict__ grid,
    int total_points)
{
    int t = blockIdx.x * blockDim.x + threadIdx.x;
    int p = t >> 4;          // point index
    int k = t & 15;          // feature-pair index
    if (p >= total_points) return;

    // All 16 lanes of the group load the same 3 coords (cache broadcast).
    float cx = coords[p * 3 + 0];
    float cy = coords[p * 3 + 1];
    float cz = coords[p * 3 + 2];

    // jnp.round = round-half-to-even; rintf matches (default RNE mode).
    // GRID_RES = 1.0 so (c + 35.0f)/1.0f == c + 35.0f exactly.
    int gx = (int)rintf(cx + MAX_DIST_F);
    int gy = (int)rintf(cy + MAX_DIST_F);
    int gz = (int)rintf(cz + MAX_DIST_F);

    bool in_box = (gx >= 0) & (gx < BOX) &
                  (gy >= 0) & (gy < BOX) &
                  (gz >= 0) & (gz < BOX);
    if (!in_box) return;     // reference adds 0 at clamped index -> no-op

    v2f v = *(const v2f*)&features[(size_t)p * NF + 2 * k];
    size_t idx = (((size_t)gx * BOX + gy) * BOX + gz) * NF + 2 * k;

#if defined(HAVE_PK_FADD)
    typedef __attribute__((address_space(1))) v2f gv2f;
    __builtin_amdgcn_global_atomic_fadd_v2f32((gv2f*)(grid + idx), v);
#else
    // Fallback: scalar HW atomics (== R5 path op count).
    unsafeAtomicAdd(grid + idx + 0, v.x);
    unsafeAtomicAdd(grid + idx + 1, v.y);
#endif
}

extern "C" void kernel_launch(void* const* d_in, const int* in_sizes, int n_in,
                              void* d_out, int out_size, void* d_ws, size_t ws_size,
                              hipStream_t stream) {
    const float* coords   = (const float*)d_in[0];  // [B,N,3] fp32
    const float* features = (const float*)d_in[1];  // [B,N,F] fp32
    float* out = (float*)d_out;                     // [B,71,71,71,F] fp32

    // out_size is the logical output BYTE count (366,500,864). One full-size
    // rocclr fill (~6.3 TB/s streaming). Do NOT split/fuse/NT this — every
    // such variant regressed (see model note).
    hipMemsetAsync(out, 0, (size_t)out_size, stream);

    int total_points = in_sizes[0] / 3;             // B*N = 131072
    int total_threads = total_points * 16;          // 16 lanes per point
    int blocks = (total_threads + 255) / 256;       // 8192
    MakeGrid_scatter_kernel<<<blocks, 256, 0, stream>>>(coords, features, out, total_points);
}

// Round 8
// 327.817 us; speedup vs baseline: 1.4810x; 1.0183x over previous
//
#include <hip/hip_runtime.h>

#define BOX 71
#define NF 32
#define MAX_DIST_F 35.0f

// ===========================================================================
// TERMINAL structure (session model, R0-R7, seven differentials):
//  - Harness poisons the 4x-overallocated output (1.466 GB fill, ~230-240 us)
//    INSIDE the timed window, same stream, every iteration. Untouchable:
//    same-stream ordering means it cannot be overlapped, and it re-dirties
//    the whole buffer so the full zero is compulsory.
//  - Full 366 MB zero via one rocclr fill: ~58 us @ ~6.3 TB/s (the achievable
//    ceiling). Every custom zeroing variant ran >=2x slower (plain/NT stores
//    ~2.4 TB/s): R3 NT-split 395, R4 fused zero+scatter 383, R6 CSR-gather 485.
//  - Scatter ~31 us: bound by memory-side dword-atomic throughput, NOT
//    instruction count — R7's packed v2f32 atomics (half the instructions)
//    were neutral (TCC processes pk_add as 2 dword RMWs). Contention is mild
//    (~1 point/cell at the Gaussian center) so duplicate-aggregation has no
//    headroom; the CSR gather alternative cost +157 us.
//  - Floor = poison (227-239) + fill (58) + scatter (31) ~= 316-328 us.
//    This kernel measures 328.3 us => at the structural roofline.
// ===========================================================================

// One 32-lane group per point: lane f handles feature f.
// features layout [B,N,F] -> consecutive lanes read consecutive floats (coalesced).
// atomic target grid[0, x, y, z, f] -> 32 consecutive floats per point (coalesced burst).
__global__ __launch_bounds__(256) void MakeGrid_scatter_kernel(
    const float* __restrict__ coords,
    const float* __restrict__ features,
    float* __restrict__ grid,
    int total_points)
{
    int t = blockIdx.x * blockDim.x + threadIdx.x;
    int p = t >> 5;          // point index
    int f = t & 31;          // feature index
    if (p >= total_points) return;

    // All 32 lanes of the group load the same 3 coords (cache broadcast).
    float cx = coords[p * 3 + 0];
    float cy = coords[p * 3 + 1];
    float cz = coords[p * 3 + 2];

    // jnp.round = round-half-to-even; rintf matches (default RNE rounding mode).
    // GRID_RES = 1.0 so (c + 35.0f) / 1.0f == c + 35.0f exactly.
    int gx = (int)rintf(cx + MAX_DIST_F);
    int gy = (int)rintf(cy + MAX_DIST_F);
    int gz = (int)rintf(cz + MAX_DIST_F);

    bool in_box = (gx >= 0) & (gx < BOX) &
                  (gy >= 0) & (gy < BOX) &
                  (gz >= 0) & (gz < BOX);
    if (!in_box) return;     // reference adds 0 at clamped index -> no-op

    float v = features[(size_t)p * NF + f];
    size_t idx = (((size_t)gx * BOX + gy) * BOX + gz) * NF + f;
    // unsafeAtomicAdd == HW global_atomic_add_f32 (verified identical to
    // atomicAdd in R5: both 328.3 us). Device scope -> correct across XCDs.
#if defined(__AMDGCN__)
    unsafeAtomicAdd(grid + idx, v);
#else
    atomicAdd(grid + idx, v);
#endif
}

extern "C" void kernel_launch(void* const* d_in, const int* in_sizes, int n_in,
                              void* d_out, int out_size, void* d_ws, size_t ws_size,
                              hipStream_t stream) {
    const float* coords   = (const float*)d_in[0];  // [B,N,3] fp32
    const float* features = (const float*)d_in[1];  // [B,N,F] fp32
    float* out = (float*)d_out;                     // [B,71,71,71,F] fp32

    // out_size is the logical output BYTE count (366,500,864). One full-size
    // rocclr fill. Do NOT split/fuse/NT this — every such variant regressed
    // (see model note above).
    hipMemsetAsync(out, 0, (size_t)out_size, stream);

    int total_points = in_sizes[0] / 3;             // B*N = 131072
    int total_threads = total_points * NF;
    int blocks = (total_threads + 255) / 256;
    MakeGrid_scatter_kernel<<<blocks, 256, 0, stream>>>(coords, features, out, total_points);
}